// Round 2
// baseline (671.610 us; speedup 1.0000x reference)
//
#include <hip/hip_runtime.h>
#include <hip/hip_bf16.h>

// Problem: B=32, S=4096, D=512.
// out = [att_weights (32,4096) fp32 | hidden_output (32,512) fp32]
//
// Fused flash-style pipeline, occupancy-first:
//   wconv:  Ws -> bf16 tiled (512 KB, L2-resident)
//   t:      t[b,h] = targ . Wt
//   fused:  2048 blocks x 512 thr, 64 s-rows each. A staged once to LDS
//           (1 barrier); B frags global->reg (L2); NO barriers in main loop.
//           Local softmax + ctx partial from resident bf16 A tile.
//   final2: merge 64 tiles/batch (one wave), att + hidden_output

typedef __attribute__((ext_vector_type(8))) short bf16x8;
typedef __attribute__((ext_vector_type(4))) float f32x4;

#define L2E 1.4426950408889634f

// packed fp32x2 -> bf16x2 (RNE); lowers to v_cvt_pk_bf16_f32 on gfx950
static __device__ __forceinline__ unsigned cvt2(float a, float b) {
    union { __hip_bfloat162 h; unsigned u; } v;
    v.h = __float22bfloat162_rn(make_float2(a, b));
    return v.u;
}
static __device__ __forceinline__ float bits2f(unsigned u) {
    union { unsigned u; float f; } x; x.u = u; return x.f;
}
static __device__ __forceinline__ float fast_tanh(float x) {
    float ex = exp2f(x * 2.8853900817779268f);
    return 1.0f - 2.0f / (ex + 1.0f);
}

// ws layout (bytes):
#define WS_WBF   0L          // 512 KB  Ws bf16 tiled+swizzled
#define WS_T     524288L     // 64 KB   t (32x512 f32)
#define WS_E     589824L     // 512 KB  e (32x4096 f32)
#define WS_MST   1114112L    // 16 KB   per-tile (m_L, sum_L) x 2048
#define WS_CTXP  1130496L    // 4 MB    2048 x 512 f32 ctx partials

// ---- Ws (W[:,512:]) -> bf16, tile-contiguous + chunk-swizzled ----
// tile (hx,kt): 128 rows x 32 k; position p=(r,u') stores data unit u'^((r>>1)&3)
__global__ void wconv_kernel(const float* __restrict__ W, short* __restrict__ wbf) {
    const int gid = blockIdx.x * 256 + threadIdx.x;       // [0, 32768)
    const int tile = gid >> 9, p = gid & 511;
    const int hx = tile >> 4, ktile = tile & 15;
    const int r = p >> 2, up = p & 3;
    const int u = up ^ ((r >> 1) & 3);
    const float* s = W + (long)(hx * 128 + r) * 1024 + 512 + ktile * 32 + u * 8;
    float4 v0 = *(const float4*)(s);
    float4 v1 = *(const float4*)(s + 4);
    uint4 pk;
    pk.x = cvt2(v0.x, v0.y); pk.y = cvt2(v0.z, v0.w);
    pk.z = cvt2(v1.x, v1.y); pk.w = cvt2(v1.z, v1.w);
    ((uint4*)wbf)[gid] = pk;
}

// ---- t[b,h] = sum_d targ[b,d] * W[h, d] ----
__global__ void t_kernel(const float* __restrict__ targ,
                         const float* __restrict__ W,
                         float* __restrict__ t) {
    __shared__ float tg[512];
    const int b = blockIdx.x >> 2;
    const int hbase = (blockIdx.x & 3) * 128;
    const int tid = threadIdx.x;
    tg[tid]       = targ[b * 512 + tid];
    tg[tid + 256] = targ[b * 512 + tid + 256];
    __syncthreads();
    const int lane = tid & 63, wave = tid >> 6;
    for (int h = hbase + wave; h < hbase + 128; h += 4) {
        const float* wr = W + (long)h * 1024;
        float s = 0.f;
        #pragma unroll
        for (int i = 0; i < 2; i++) {
            const int d = lane * 4 + i * 256;
            float4 wv = *(const float4*)(wr + d);
            s += wv.x * tg[d] + wv.y * tg[d + 1] + wv.z * tg[d + 2] + wv.w * tg[d + 3];
        }
        s += __shfl_xor(s, 1);  s += __shfl_xor(s, 2);  s += __shfl_xor(s, 4);
        s += __shfl_xor(s, 8);  s += __shfl_xor(s, 16); s += __shfl_xor(s, 32);
        if (lane == 0) t[b * 512 + h] = s;
    }
}

// ---- fused: 64 s-rows/block, full-h GEMM + local softmax + ctx partial ----
__global__ __launch_bounds__(512, 4)
void fused_kernel(const float* __restrict__ src,
                  const short* __restrict__ wbf,
                  const float* __restrict__ t,
                  const float* __restrict__ V,
                  const float* __restrict__ mask,
                  float* __restrict__ e_ws,
                  float* __restrict__ mstats,
                  float* __restrict__ ctxp) {
    // As: 64 rows x 512 k bf16 (64 KB), 16B-chunk XOR swizzle: chunk ^= (row&7)
    __shared__ __align__(16) short As[64 * 512];
    __shared__ float er[4][64];
    __shared__ float pbuf[64];
    __shared__ float cbuf[512];

    const int tid = threadIdx.x;
    const int mt  = blockIdx.x;            // 0..2047  (= b*64 + stile)
    const int b   = mt >> 6;
    const long m0 = (long)mt * 64;         // global s-row base

    const int lane = tid & 63, wave = tid >> 6;   // 8 waves
    const int wm = wave & 1, wn = wave >> 1;      // 2 x 4 wave grid
    const int lr = lane & 15, quad = lane >> 4;
    const int l7 = lr & 7;

    // ---- prologue: stage A tile fp32 -> bf16 (packed cvt) -> swizzled LDS ----
    {
        const int row = tid >> 3, cp = tid & 7;   // 8 threads per row
        const float* ap = src + (m0 + row) * 512 + cp * 64;
        short* abase = As + row * 512;
        const int r7 = row & 7;
        #pragma unroll
        for (int i = 0; i < 4; ++i) {
            float4 v0 = *(const float4*)(ap + i * 16);
            float4 v1 = *(const float4*)(ap + i * 16 + 4);
            float4 v2 = *(const float4*)(ap + i * 16 + 8);
            float4 v3 = *(const float4*)(ap + i * 16 + 12);
            uint4 pA, pB;
            pA.x = cvt2(v0.x, v0.y); pA.y = cvt2(v0.z, v0.w);
            pA.z = cvt2(v1.x, v1.y); pA.w = cvt2(v1.z, v1.w);
            pB.x = cvt2(v2.x, v2.y); pB.y = cvt2(v2.z, v2.w);
            pB.z = cvt2(v3.x, v3.y); pB.w = cvt2(v3.z, v3.w);
            const int cc = cp * 8 + i * 2;
            *(uint4*)(abase + ((cc    ) ^ r7) * 8) = pA;
            *(uint4*)(abase + ((cc + 1) ^ r7) * 8) = pB;
        }
    }
    __syncthreads();   // the ONLY barrier before the epilogue phases

    // per-lane invariant B offsets (shorts) within a 128x32 wbf tile
    int boff[2];
    #pragma unroll
    for (int ni = 0; ni < 2; ++ni) {
        const int row = wn * 32 + ni * 16 + lr;
        boff[ni] = row * 32 + (quad ^ ((row >> 1) & 3)) * 8;
    }

    float esacc[2][4];
    #pragma unroll
    for (int mi = 0; mi < 2; ++mi)
        #pragma unroll
        for (int r = 0; r < 4; ++r) esacc[mi][r] = 0.f;

    for (int hx = 0; hx < 4; ++hx) {
        f32x4 acc[2][2];
        #pragma unroll
        for (int mi = 0; mi < 2; ++mi)
            #pragma unroll
            for (int ni = 0; ni < 2; ++ni)
                acc[mi][ni] = (f32x4){0.f, 0.f, 0.f, 0.f};

        const short* hbase = wbf + (long)hx * 16 * 4096;
        #pragma unroll
        for (int kt = 0; kt < 16; ++kt) {
            bf16x8 af[2], bfr[2];
            #pragma unroll
            for (int mi = 0; mi < 2; ++mi) {
                const int row = wm * 32 + mi * 16 + lr;
                af[mi] = *(const bf16x8*)(As + row * 512 + (((kt * 4 + quad) ^ l7) * 8));
            }
            const short* bt = hbase + kt * 4096;
            #pragma unroll
            for (int ni = 0; ni < 2; ++ni)
                bfr[ni] = *(const bf16x8*)(bt + boff[ni]);   // global (L2) -> reg
            #pragma unroll
            for (int mi = 0; mi < 2; ++mi)
                #pragma unroll
                for (int ni = 0; ni < 2; ++ni)
                    acc[mi][ni] = __builtin_amdgcn_mfma_f32_16x16x32_bf16(
                        af[mi], bfr[ni], acc[mi][ni], 0, 0, 0);
        }

        // e partial for this hx chunk; accumulate in registers (same owner lane)
        const float* trow = t + b * 512;
        float th[2], vv[2];
        #pragma unroll
        for (int ni = 0; ni < 2; ++ni) {
            const int h = hx * 128 + wn * 32 + ni * 16 + lr;
            th[ni] = trow[h];
            vv[ni] = V[h];
        }
        #pragma unroll
        for (int mi = 0; mi < 2; ++mi) {
            #pragma unroll
            for (int r = 0; r < 4; ++r) {
                float es = fast_tanh(acc[mi][0][r] + th[0]) * vv[0]
                         + fast_tanh(acc[mi][1][r] + th[1]) * vv[1];
                es += __shfl_xor(es, 1);
                es += __shfl_xor(es, 2);
                es += __shfl_xor(es, 4);
                es += __shfl_xor(es, 8);
                esacc[mi][r] += es;
            }
        }
    }

    // deposit per-(wn) partials: m = wm*32 + mi*16 + quad*4 + r
    if (lr == 0) {
        #pragma unroll
        for (int mi = 0; mi < 2; ++mi)
            #pragma unroll
            for (int r = 0; r < 4; ++r)
                er[wn][wm * 32 + mi * 16 + quad * 4 + r] = esacc[mi][r];
    }
    __syncthreads();

    // ---- block-local softmax over 64 rows (wave 0 only) ----
    if (tid < 64) {
        const float myE = er[0][tid] + er[1][tid] + er[2][tid] + er[3][tid];
        float mx = myE;
        #pragma unroll
        for (int m = 1; m <= 32; m <<= 1) mx = fmaxf(mx, __shfl_xor(mx, m));
        const float pv = exp2f((myE - mx) * L2E);
        float sv = pv;
        #pragma unroll
        for (int m = 1; m <= 32; m <<= 1) sv += __shfl_xor(sv, m);
        e_ws[m0 + tid] = myE;
        pbuf[tid] = pv * mask[m0 + tid];     // masked p for ctx; sum unmasked
        if (tid == 0) { mstats[mt * 2] = mx; mstats[mt * 2 + 1] = sv; }
    }
    __syncthreads();

    // ---- ctx partial: ctxp[mt][d] = sum_s p_s * src_bf16[s][d] (A in LDS) ----
    const int sg = tid >> 8;                // s-half 0/1
    const int d0 = (tid & 255) * 2;
    const int cb = d0 >> 3, coff = d0 & 7;
    float a0 = 0.f, a1 = 0.f;
    #pragma unroll 8
    for (int s = sg * 32; s < sg * 32 + 32; ++s) {
        const unsigned u = *(const unsigned*)(As + s * 512 + ((cb ^ (s & 7)) * 8) + coff);
        const float w = pbuf[s];
        a0 += w * bits2f(u << 16);
        a1 += w * bits2f(u & 0xffff0000u);
    }
    if (sg) { cbuf[d0] = a0; cbuf[d0 + 1] = a1; }
    __syncthreads();
    if (!sg) {
        a0 += cbuf[d0];
        a1 += cbuf[d0 + 1];
        ctxp[(long)mt * 512 + d0]     = a0;
        ctxp[(long)mt * 512 + d0 + 1] = a1;
    }
}

// ---- finalize: merge 64 tiles per batch; att + hidden_output ----
__global__ void final2_kernel(const float* __restrict__ e_ws,
                              const float* __restrict__ mstats,
                              const float* __restrict__ ctxp,
                              const float* __restrict__ mask,
                              const float* __restrict__ targ,
                              float* __restrict__ att,
                              float* __restrict__ outh) {
    const int b = blockIdx.x, tid = threadIdx.x;
    __shared__ float wL[64];
    __shared__ float bc[2];
    if (tid < 64) {
        const float mv = mstats[(b * 64 + tid) * 2];
        const float sv = mstats[(b * 64 + tid) * 2 + 1];
        float M = mv;
        #pragma unroll
        for (int m = 1; m <= 32; m <<= 1) M = fmaxf(M, __shfl_xor(M, m));
        float sc = sv * exp2f((mv - M) * L2E);
        #pragma unroll
        for (int m = 1; m <= 32; m <<= 1) sc += __shfl_xor(sc, m);
        wL[tid] = exp2f((mv - M) * L2E) / sc;
        if (tid == 0) { bc[0] = M; bc[1] = sc; }
    }
    __syncthreads();
    const float M = bc[0], invS = 1.0f / bc[1];
    #pragma unroll
    for (int i = 0; i < 16; i++) {
        const int s = i * 256 + tid;
        const long idx = (long)b * 4096 + s;
        att[idx] = exp2f((e_ws[idx] - M) * L2E) * invS * mask[idx];
    }
    #pragma unroll
    for (int dd = 0; dd < 2; dd++) {
        const int d = dd * 256 + tid;
        float a = targ[b * 512 + d];
        for (int L = 0; L < 64; L++)
            a += wL[L] * ctxp[((long)(b * 64 + L)) * 512 + d];
        outh[b * 512 + d] = a;
    }
}

extern "C" void kernel_launch(void* const* d_in, const int* in_sizes, int n_in,
                              void* d_out, int out_size, void* d_ws, size_t ws_size,
                              hipStream_t stream) {
    const float* targ = (const float*)d_in[0];
    const float* src  = (const float*)d_in[1];
    const float* mask = (const float*)d_in[2];
    const float* W    = (const float*)d_in[3];
    const float* V    = (const float*)d_in[4];

    float* att  = (float*)d_out;
    float* outh = (float*)d_out + 131072;

    char* ws = (char*)d_ws;
    short* wbf   = (short*)(ws + WS_WBF);
    float* t     = (float*)(ws + WS_T);
    float* e     = (float*)(ws + WS_E);
    float* mst   = (float*)(ws + WS_MST);
    float* ctxp  = (float*)(ws + WS_CTXP);

    wconv_kernel<<<128, 256, 0, stream>>>(W, wbf);
    t_kernel<<<128, 256, 0, stream>>>(targ, W, t);
    fused_kernel<<<2048, 512, 0, stream>>>(src, wbf, t, V, mask, e, mst, ctxp);
    final2_kernel<<<32, 256, 0, stream>>>(e, mst, ctxp, mask, targ, att, outh);
}

// Round 4
// 465.135 us; speedup vs baseline: 1.4439x; 1.4439x over previous
//
#include <hip/hip_runtime.h>
#include <hip/hip_bf16.h>

// Problem: B=32, S=4096, D=512.
// out = [att_weights (32,4096) fp32 | hidden_output (32,512) fp32]
//
// Fused flash-style pipeline:
//   prep:   Ws -> bf16 tiled+swizzled (512 KB) ; t[b,h] = targ . Wt
//   fused:  2048 blocks x 256 thr (4 waves), 64 s-rows each.
//           A staged once to LDS via NONTEMPORAL loads (src read ONCE, caches
//           protected); wave w owns h-slice w*128 (no B redundancy); B frags
//           global->reg double-buffered; NO barriers in the K loop.
//           Local softmax + ctx partial from resident bf16 A tile.
//   final2: merge 64 tiles/batch, att + hidden_output

typedef __attribute__((ext_vector_type(8))) short bf16x8;
typedef __attribute__((ext_vector_type(4))) float f32x4;

#define L2E 1.4426950408889634f

// packed fp32x2 -> bf16x2 (RNE); lowers to v_cvt_pk_bf16_f32 on gfx950
static __device__ __forceinline__ unsigned cvt2(float a, float b) {
    union { __hip_bfloat162 h; unsigned u; } v;
    v.h = __float22bfloat162_rn(make_float2(a, b));
    return v.u;
}
static __device__ __forceinline__ float bits2f(unsigned u) {
    union { unsigned u; float f; } x; x.u = u; return x.f;
}
static __device__ __forceinline__ float fast_tanh(float x) {
    float ex = exp2f(x * 2.8853900817779268f);
    return 1.0f - 2.0f / (ex + 1.0f);
}

// ws layout (bytes):
#define WS_WBF   0L          // 512 KB  Ws bf16 tiled+swizzled
#define WS_T     524288L     // 64 KB   t (32x512 f32)
#define WS_E     589824L     // 512 KB  e (32x4096 f32)
#define WS_MST   1114112L    // 16 KB   per-tile (m_L, sum_L) x 2048
#define WS_CTXP  1130496L    // 4 MB    2048 x 512 f32 ctx partials

// ---- prep: [0,128) wconv  Ws->bf16 tiled+swizzled ; [128,256) t = targ.Wt ----
// wbf tile (hx,kt): 128 rows x 32 k; position p=(r,u') stores data unit u'^((r>>1)&3)
__global__ void prep_kernel(const float* __restrict__ W,
                            const float* __restrict__ targ,
                            short* __restrict__ wbf,
                            float* __restrict__ t) {
    if (blockIdx.x < 128) {
        const int gid = blockIdx.x * 256 + threadIdx.x;       // [0, 32768)
        const int tile = gid >> 9, p = gid & 511;
        const int hx = tile >> 4, ktile = tile & 15;
        const int r = p >> 2, up = p & 3;
        const int u = up ^ ((r >> 1) & 3);
        const float* s = W + (long)(hx * 128 + r) * 1024 + 512 + ktile * 32 + u * 8;
        float4 v0 = *(const float4*)(s);
        float4 v1 = *(const float4*)(s + 4);
        uint4 pk;
        pk.x = cvt2(v0.x, v0.y); pk.y = cvt2(v0.z, v0.w);
        pk.z = cvt2(v1.x, v1.y); pk.w = cvt2(v1.z, v1.w);
        ((uint4*)wbf)[gid] = pk;
        return;
    }
    __shared__ float tg[512];
    const int bid = blockIdx.x - 128;
    const int b = bid >> 2;
    const int hbase = (bid & 3) * 128;
    const int tid = threadIdx.x;
    tg[tid]       = targ[b * 512 + tid];
    tg[tid + 256] = targ[b * 512 + tid + 256];
    __syncthreads();
    const int lane = tid & 63, wave = tid >> 6;
    for (int h = hbase + wave; h < hbase + 128; h += 4) {
        const float* wr = W + (long)h * 1024;
        float s = 0.f;
        #pragma unroll
        for (int i = 0; i < 2; i++) {
            const int d = lane * 4 + i * 256;
            float4 wv = *(const float4*)(wr + d);
            s += wv.x * tg[d] + wv.y * tg[d + 1] + wv.z * tg[d + 2] + wv.w * tg[d + 3];
        }
        s += __shfl_xor(s, 1);  s += __shfl_xor(s, 2);  s += __shfl_xor(s, 4);
        s += __shfl_xor(s, 8);  s += __shfl_xor(s, 16); s += __shfl_xor(s, 32);
        if (lane == 0) t[b * 512 + h] = s;
    }
}

// ---- fused: 64 s-rows/block, full-h GEMM + local softmax + ctx partial ----
__global__ __launch_bounds__(256, 2)
void fused_kernel(const float* __restrict__ src,
                  const short* __restrict__ wbf,
                  const float* __restrict__ t,
                  const float* __restrict__ V,
                  const float* __restrict__ mask,
                  float* __restrict__ e_ws,
                  float* __restrict__ mstats,
                  float* __restrict__ ctxp) {
    // As: 64 rows x 512 k bf16 (64 KB), 16B-chunk XOR swizzle: chunk ^= (row&7)
    __shared__ __align__(16) short As[64 * 512];
    __shared__ float er[4][64];
    __shared__ float pbuf[64];

    const int tid = threadIdx.x;
    const int mt  = blockIdx.x;            // 0..2047  (= b*64 + stile)
    const int b   = mt >> 6;
    const long m0 = (long)mt * 64;         // global s-row base

    const int lane = tid & 63, wave = tid >> 6;   // 4 waves; wave = hx slice
    const int lr = lane & 15, quad = lane >> 4;
    const int l7 = lr & 7;

    // ---- prologue: stage A (nontemporal: protect L2/L3 for wbf) ----
    {
        const int row = tid >> 2, cp4 = tid & 3, r7 = row & 7;
        const float* ap = src + (m0 + row) * 512;
        short* abase = As + row * 512;
        #pragma unroll
        for (int j = 0; j < 16; ++j) {
            const int kb = j * 32 + cp4 * 8;
            f32x4 v0 = __builtin_nontemporal_load((const f32x4*)(ap + kb));
            f32x4 v1 = __builtin_nontemporal_load((const f32x4*)(ap + kb + 4));
            uint4 pk;
            pk.x = cvt2(v0.x, v0.y); pk.y = cvt2(v0.z, v0.w);
            pk.z = cvt2(v1.x, v1.y); pk.w = cvt2(v1.z, v1.w);
            *(uint4*)(abase + (((j * 4 + cp4) ^ r7) * 8)) = pk;
        }
    }
    __syncthreads();   // the ONLY barrier before the epilogue phases

    // per-lane invariant B offsets (shorts) within this wave's 128x32 wbf tiles
    const short* bstream = wbf + (long)wave * 16 * 4096;   // wave owns hx = wave
    int boff[8];
    #pragma unroll
    for (int ni = 0; ni < 8; ++ni) {
        const int row = ni * 16 + lr;
        boff[ni] = row * 32 + (quad ^ ((row >> 1) & 3)) * 8;
    }

    f32x4 acc[4][8];
    #pragma unroll
    for (int mi = 0; mi < 4; ++mi)
        #pragma unroll
        for (int ni = 0; ni < 8; ++ni)
            acc[mi][ni] = (f32x4){0.f, 0.f, 0.f, 0.f};

    bf16x8 b0[8], b1[8], af[4];
    #pragma unroll
    for (int ni = 0; ni < 8; ++ni)
        b0[ni] = *(const bf16x8*)(bstream + boff[ni]);          // kt = 0

    #pragma unroll
    for (int kt = 0; kt < 16; kt += 2) {
        // prefetch kt+1 (first half) while computing kt's first half
        #pragma unroll
        for (int ni = 0; ni < 4; ++ni)
            b1[ni] = *(const bf16x8*)(bstream + (kt + 1) * 4096 + boff[ni]);
        #pragma unroll
        for (int mi = 0; mi < 4; ++mi)
            af[mi] = *(const bf16x8*)(As + (mi * 16 + lr) * 512 +
                                      (((kt * 4 + quad) ^ l7) * 8));
        #pragma unroll
        for (int mi = 0; mi < 4; ++mi)
            #pragma unroll
            for (int ni = 0; ni < 4; ++ni)
                acc[mi][ni] = __builtin_amdgcn_mfma_f32_16x16x32_bf16(
                    af[mi], b0[ni], acc[mi][ni], 0, 0, 0);
        #pragma unroll
        for (int ni = 4; ni < 8; ++ni)
            b1[ni] = *(const bf16x8*)(bstream + (kt + 1) * 4096 + boff[ni]);
        #pragma unroll
        for (int mi = 0; mi < 4; ++mi)
            #pragma unroll
            for (int ni = 4; ni < 8; ++ni)
                acc[mi][ni] = __builtin_amdgcn_mfma_f32_16x16x32_bf16(
                    af[mi], b0[ni], acc[mi][ni], 0, 0, 0);

        // prefetch kt+2 while computing kt+1
        if (kt + 2 < 16) {
            #pragma unroll
            for (int ni = 0; ni < 4; ++ni)
                b0[ni] = *(const bf16x8*)(bstream + (kt + 2) * 4096 + boff[ni]);
        }
        #pragma unroll
        for (int mi = 0; mi < 4; ++mi)
            af[mi] = *(const bf16x8*)(As + (mi * 16 + lr) * 512 +
                                      ((((kt + 1) * 4 + quad) ^ l7) * 8));
        #pragma unroll
        for (int mi = 0; mi < 4; ++mi)
            #pragma unroll
            for (int ni = 0; ni < 4; ++ni)
                acc[mi][ni] = __builtin_amdgcn_mfma_f32_16x16x32_bf16(
                    af[mi], b1[ni], acc[mi][ni], 0, 0, 0);
        if (kt + 2 < 16) {
            #pragma unroll
            for (int ni = 4; ni < 8; ++ni)
                b0[ni] = *(const bf16x8*)(bstream + (kt + 2) * 4096 + boff[ni]);
        }
        #pragma unroll
        for (int mi = 0; mi < 4; ++mi)
            #pragma unroll
            for (int ni = 4; ni < 8; ++ni)
                acc[mi][ni] = __builtin_amdgcn_mfma_f32_16x16x32_bf16(
                    af[mi], b1[ni], acc[mi][ni], 0, 0, 0);
    }

    // ---- e partial for this wave's 128 h; C/D: col=lr (h), row=quad*4+r (s) ----
    const float* trow = t + b * 512;
    float th[8], vv[8];
    #pragma unroll
    for (int ni = 0; ni < 8; ++ni) {
        const int h = wave * 128 + ni * 16 + lr;
        th[ni] = trow[h];
        vv[ni] = V[h];
    }
    #pragma unroll
    for (int mi = 0; mi < 4; ++mi) {
        #pragma unroll
        for (int r = 0; r < 4; ++r) {
            float es = 0.f;
            #pragma unroll
            for (int ni = 0; ni < 8; ++ni)
                es += fast_tanh(acc[mi][ni][r] + th[ni]) * vv[ni];
            es += __shfl_xor(es, 1);
            es += __shfl_xor(es, 2);
            es += __shfl_xor(es, 4);
            es += __shfl_xor(es, 8);
            if (lr == 0) er[wave][mi * 16 + quad * 4 + r] = es;
        }
    }
    __syncthreads();

    // ---- block-local softmax over 64 rows (wave 0 only) ----
    if (tid < 64) {
        const float myE = er[0][tid] + er[1][tid] + er[2][tid] + er[3][tid];
        float mx = myE;
        #pragma unroll
        for (int m = 1; m <= 32; m <<= 1) mx = fmaxf(mx, __shfl_xor(mx, m));
        const float pv = exp2f((myE - mx) * L2E);
        float sv = pv;
        #pragma unroll
        for (int m = 1; m <= 32; m <<= 1) sv += __shfl_xor(sv, m);
        e_ws[m0 + tid] = myE;
        pbuf[tid] = pv * mask[m0 + tid];     // masked p for ctx; sum unmasked
        if (tid == 0) { mstats[mt * 2] = mx; mstats[mt * 2 + 1] = sv; }
    }
    __syncthreads();

    // ---- ctx partial: ctxp[mt][d] = sum_s p_s * src_bf16[s][d] (A in LDS) ----
    const int d0 = tid * 2;
    const int cb = d0 >> 3, coff = d0 & 7;
    float a0 = 0.f, a1 = 0.f;
    #pragma unroll 8
    for (int s = 0; s < 64; ++s) {
        const unsigned u = *(const unsigned*)(As + s * 512 + ((cb ^ (s & 7)) * 8) + coff);
        const float w = pbuf[s];
        a0 += w * bits2f(u << 16);
        a1 += w * bits2f(u & 0xffff0000u);
    }
    ctxp[(long)mt * 512 + d0]     = a0;
    ctxp[(long)mt * 512 + d0 + 1] = a1;
}

// ---- finalize: merge 64 tiles per batch; att + hidden_output ----
__global__ void final2_kernel(const float* __restrict__ e_ws,
                              const float* __restrict__ mstats,
                              const float* __restrict__ ctxp,
                              const float* __restrict__ mask,
                              const float* __restrict__ targ,
                              float* __restrict__ att,
                              float* __restrict__ outh) {
    const int b = blockIdx.x, tid = threadIdx.x;
    __shared__ float wL[64];
    __shared__ float bc[2];
    if (tid < 64) {
        const float mv = mstats[(b * 64 + tid) * 2];
        const float sv = mstats[(b * 64 + tid) * 2 + 1];
        float M = mv;
        #pragma unroll
        for (int m = 1; m <= 32; m <<= 1) M = fmaxf(M, __shfl_xor(M, m));
        float sc = sv * exp2f((mv - M) * L2E);
        #pragma unroll
        for (int m = 1; m <= 32; m <<= 1) sc += __shfl_xor(sc, m);
        wL[tid] = exp2f((mv - M) * L2E) / sc;
        if (tid == 0) { bc[0] = M; bc[1] = sc; }
    }
    __syncthreads();
    const float M = bc[0], invS = 1.0f / bc[1];
    #pragma unroll
    for (int i = 0; i < 16; i++) {
        const int s = i * 256 + tid;
        const long idx = (long)b * 4096 + s;
        att[idx] = exp2f((e_ws[idx] - M) * L2E) * invS * mask[idx];
    }
    #pragma unroll
    for (int dd = 0; dd < 2; dd++) {
        const int d = dd * 256 + tid;
        float a = targ[b * 512 + d];
        #pragma unroll 4
        for (int L = 0; L < 64; L++)
            a += wL[L] * ctxp[((long)(b * 64 + L)) * 512 + d];
        outh[b * 512 + d] = a;
    }
}

extern "C" void kernel_launch(void* const* d_in, const int* in_sizes, int n_in,
                              void* d_out, int out_size, void* d_ws, size_t ws_size,
                              hipStream_t stream) {
    const float* targ = (const float*)d_in[0];
    const float* src  = (const float*)d_in[1];
    const float* mask = (const float*)d_in[2];
    const float* W    = (const float*)d_in[3];
    const float* V    = (const float*)d_in[4];

    float* att  = (float*)d_out;
    float* outh = (float*)d_out + 131072;

    char* ws = (char*)d_ws;
    short* wbf   = (short*)(ws + WS_WBF);
    float* t     = (float*)(ws + WS_T);
    float* e     = (float*)(ws + WS_E);
    float* mst   = (float*)(ws + WS_MST);
    float* ctxp  = (float*)(ws + WS_CTXP);

    prep_kernel<<<256, 256, 0, stream>>>(W, targ, wbf, t);
    fused_kernel<<<2048, 256, 0, stream>>>(src, wbf, t, V, mask, e, mst, ctxp);
    final2_kernel<<<32, 256, 0, stream>>>(e, mst, ctxp, mask, targ, att, outh);
}

// Round 5
// 454.420 us; speedup vs baseline: 1.4780x; 1.0236x over previous
//
#include <hip/hip_runtime.h>
#include <hip/hip_bf16.h>

// Problem: B=32, S=4096, D=512.
// out = [att_weights (32,4096) fp32 | hidden_output (32,512) fp32]
//
// Fused flash-style pipeline:
//   prep:   Ws -> bf16 tiled+swizzled (512 KB) ; t[b,h] = targ . Wt
//   fused:  2048 blocks x 512 thr (8 waves), 64 s-rows each. Wave w owns
//           64 h (exact cover, no B redundancy). A staged once to LDS via
//           nontemporal loads; B global->reg double-buffered; no barriers
//           in the K loop. Raw v_exp/v_rcp for tanh. Local softmax + ctx
//           partial from resident bf16 A tile.
//   final2: merge 64 tiles/batch, att + hidden_output

typedef __attribute__((ext_vector_type(8))) short bf16x8;
typedef __attribute__((ext_vector_type(4))) float f32x4;

#define L2E 1.4426950408889634f

// packed fp32x2 -> bf16x2 (RNE); lowers to v_cvt_pk_bf16_f32 on gfx950
static __device__ __forceinline__ unsigned cvt2(float a, float b) {
    union { __hip_bfloat162 h; unsigned u; } v;
    v.h = __float22bfloat162_rn(make_float2(a, b));
    return v.u;
}
static __device__ __forceinline__ float bits2f(unsigned u) {
    union { unsigned u; float f; } x; x.u = u; return x.f;
}
static __device__ __forceinline__ float fast_exp2(float x) {
    return __builtin_amdgcn_exp2f(x);
}
static __device__ __forceinline__ float fast_tanh(float x) {
    float ex = __builtin_amdgcn_exp2f(x * 2.8853900817779268f);
    return 1.0f - 2.0f * __builtin_amdgcn_rcpf(ex + 1.0f);
}

// ws layout (bytes):
#define WS_WBF   0L          // 512 KB  Ws bf16 tiled+swizzled
#define WS_T     524288L     // 64 KB   t (32x512 f32)
#define WS_E     589824L     // 512 KB  e (32x4096 f32)
#define WS_MST   1114112L    // 16 KB   per-tile (m_L, sum_L) x 2048
#define WS_CTXP  1130496L    // 4 MB    2048 x 512 f32 ctx partials

// ---- prep: [0,128) wconv  Ws->bf16 tiled+swizzled ; [128,256) t = targ.Wt ----
// wbf tile (hx,kt): 128 rows x 32 k; position p=(r,u') stores data unit u'^((r>>1)&3)
__global__ void prep_kernel(const float* __restrict__ W,
                            const float* __restrict__ targ,
                            short* __restrict__ wbf,
                            float* __restrict__ t) {
    if (blockIdx.x < 128) {
        const int gid = blockIdx.x * 256 + threadIdx.x;       // [0, 32768)
        const int tile = gid >> 9, p = gid & 511;
        const int hx = tile >> 4, ktile = tile & 15;
        const int r = p >> 2, up = p & 3;
        const int u = up ^ ((r >> 1) & 3);
        const float* s = W + (long)(hx * 128 + r) * 1024 + 512 + ktile * 32 + u * 8;
        float4 v0 = *(const float4*)(s);
        float4 v1 = *(const float4*)(s + 4);
        uint4 pk;
        pk.x = cvt2(v0.x, v0.y); pk.y = cvt2(v0.z, v0.w);
        pk.z = cvt2(v1.x, v1.y); pk.w = cvt2(v1.z, v1.w);
        ((uint4*)wbf)[gid] = pk;
        return;
    }
    __shared__ float tg[512];
    const int bid = blockIdx.x - 128;
    const int b = bid >> 2;
    const int hbase = (bid & 3) * 128;
    const int tid = threadIdx.x;
    tg[tid]       = targ[b * 512 + tid];
    tg[tid + 256] = targ[b * 512 + tid + 256];
    __syncthreads();
    const int lane = tid & 63, wave = tid >> 6;
    for (int h = hbase + wave; h < hbase + 128; h += 4) {
        const float* wr = W + (long)h * 1024;
        float s = 0.f;
        #pragma unroll
        for (int i = 0; i < 2; i++) {
            const int d = lane * 4 + i * 256;
            float4 wv = *(const float4*)(wr + d);
            s += wv.x * tg[d] + wv.y * tg[d + 1] + wv.z * tg[d + 2] + wv.w * tg[d + 3];
        }
        s += __shfl_xor(s, 1);  s += __shfl_xor(s, 2);  s += __shfl_xor(s, 4);
        s += __shfl_xor(s, 8);  s += __shfl_xor(s, 16); s += __shfl_xor(s, 32);
        if (lane == 0) t[b * 512 + h] = s;
    }
}

// ---- fused: 64 s-rows/block, full-h GEMM + local softmax + ctx partial ----
__global__ __launch_bounds__(512, 4)
void fused_kernel(const float* __restrict__ src,
                  const short* __restrict__ wbf,
                  const float* __restrict__ t,
                  const float* __restrict__ V,
                  const float* __restrict__ mask,
                  float* __restrict__ e_ws,
                  float* __restrict__ mstats,
                  float* __restrict__ ctxp) {
    // As: 64 rows x 512 k bf16 (64 KB), 16B-chunk XOR swizzle: chunk ^= (row&7)
    __shared__ __align__(16) short As[64 * 512];
    __shared__ float er[8][64];
    __shared__ float pbuf[64];
    __shared__ float cbuf[512];

    const int tid = threadIdx.x;
    const int mt  = blockIdx.x;            // 0..2047  (= b*64 + stile)
    const int b   = mt >> 6;
    const long m0 = (long)mt * 64;         // global s-row base

    const int lane = tid & 63, wave = tid >> 6;   // 8 waves; wave owns 64 h
    const int lr = lane & 15, quad = lane >> 4;
    const int l7 = lr & 7;

    // ---- prologue: stage A (nontemporal: protect L2/L3 for wbf) ----
    {
        const int row = tid >> 3, cp8 = tid & 7, r7 = row & 7;
        const float* ap = src + (m0 + row) * 512;
        short* abase = As + row * 512;
        #pragma unroll
        for (int j = 0; j < 8; ++j) {
            const int kb = j * 64 + cp8 * 8;
            f32x4 v0 = __builtin_nontemporal_load((const f32x4*)(ap + kb));
            f32x4 v1 = __builtin_nontemporal_load((const f32x4*)(ap + kb + 4));
            uint4 pk;
            pk.x = cvt2(v0.x, v0.y); pk.y = cvt2(v0.z, v0.w);
            pk.z = cvt2(v1.x, v1.y); pk.w = cvt2(v1.z, v1.w);
            *(uint4*)(abase + (((j * 8 + cp8) ^ r7) * 8)) = pk;
        }
    }
    __syncthreads();   // the ONLY barrier before the epilogue phases

    // wave w owns h-slice [w*64, w*64+64): hx tile = w>>1, half = (w&1)*64
    const short* bstream = wbf + (long)(wave >> 1) * 16 * 4096;
    const int rbase = (wave & 1) * 64;
    // per-lane B fragment pointers (advance by one 128x32 tile = 4096 shorts/kt)
    const short* bptr[4];
    #pragma unroll
    for (int ni = 0; ni < 4; ++ni) {
        const int row = rbase + ni * 16 + lr;
        bptr[ni] = bstream + row * 32 + (quad ^ ((row >> 1) & 3)) * 8;
    }

    f32x4 acc[4][4];
    #pragma unroll
    for (int mi = 0; mi < 4; ++mi)
        #pragma unroll
        for (int ni = 0; ni < 4; ++ni)
            acc[mi][ni] = (f32x4){0.f, 0.f, 0.f, 0.f};

    bf16x8 b0[4], b1[4];
    #pragma unroll
    for (int ni = 0; ni < 4; ++ni)
        b0[ni] = *(const bf16x8*)(bptr[ni]);                    // kt = 0

    #pragma unroll
    for (int kt = 0; kt < 16; kt += 2) {
        // prefetch kt+1 while computing kt
        #pragma unroll
        for (int ni = 0; ni < 4; ++ni)
            b1[ni] = *(const bf16x8*)(bptr[ni] + (kt + 1) * 4096);
        #pragma unroll
        for (int mi = 0; mi < 4; ++mi) {
            bf16x8 af = *(const bf16x8*)(As + (mi * 16 + lr) * 512 +
                                         (((kt * 4 + quad) ^ l7) * 8));
            #pragma unroll
            for (int ni = 0; ni < 4; ++ni)
                acc[mi][ni] = __builtin_amdgcn_mfma_f32_16x16x32_bf16(
                    af, b0[ni], acc[mi][ni], 0, 0, 0);
        }
        // prefetch kt+2 while computing kt+1
        if (kt + 2 < 16) {
            #pragma unroll
            for (int ni = 0; ni < 4; ++ni)
                b0[ni] = *(const bf16x8*)(bptr[ni] + (kt + 2) * 4096);
        }
        #pragma unroll
        for (int mi = 0; mi < 4; ++mi) {
            bf16x8 af = *(const bf16x8*)(As + (mi * 16 + lr) * 512 +
                                         ((((kt + 1) * 4 + quad) ^ l7) * 8));
            #pragma unroll
            for (int ni = 0; ni < 4; ++ni)
                acc[mi][ni] = __builtin_amdgcn_mfma_f32_16x16x32_bf16(
                    af, b1[ni], acc[mi][ni], 0, 0, 0);
        }
    }

    // ---- e partial for this wave's 64 h; C/D: col=lr (h), row=quad*4+r (s) ----
    const float* trow = t + b * 512;
    float th[4], vv[4];
    #pragma unroll
    for (int ni = 0; ni < 4; ++ni) {
        const int h = wave * 64 + ni * 16 + lr;
        th[ni] = trow[h];
        vv[ni] = V[h];
    }
    #pragma unroll
    for (int mi = 0; mi < 4; ++mi) {
        #pragma unroll
        for (int r = 0; r < 4; ++r) {
            float es = 0.f;
            #pragma unroll
            for (int ni = 0; ni < 4; ++ni)
                es += fast_tanh(acc[mi][ni][r] + th[ni]) * vv[ni];
            es += __shfl_xor(es, 1);
            es += __shfl_xor(es, 2);
            es += __shfl_xor(es, 4);
            es += __shfl_xor(es, 8);
            if (lr == 0) er[wave][mi * 16 + quad * 4 + r] = es;
        }
    }
    __syncthreads();

    // ---- block-local softmax over 64 rows (wave 0 only) ----
    if (tid < 64) {
        float myE = er[0][tid] + er[1][tid] + er[2][tid] + er[3][tid]
                  + er[4][tid] + er[5][tid] + er[6][tid] + er[7][tid];
        float mx = myE;
        #pragma unroll
        for (int m = 1; m <= 32; m <<= 1) mx = fmaxf(mx, __shfl_xor(mx, m));
        const float pv = fast_exp2((myE - mx) * L2E);
        float sv = pv;
        #pragma unroll
        for (int m = 1; m <= 32; m <<= 1) sv += __shfl_xor(sv, m);
        e_ws[m0 + tid] = myE;
        pbuf[tid] = pv * mask[m0 + tid];     // masked p for ctx; sum unmasked
        if (tid == 0) { mstats[mt * 2] = mx; mstats[mt * 2 + 1] = sv; }
    }
    __syncthreads();

    // ---- ctx partial: ctxp[mt][d] = sum_s p_s * src_bf16[s][d] (A in LDS) ----
    const int sg = tid >> 8;                // s-half 0/1
    const int d0 = (tid & 255) * 2;
    const int cb = d0 >> 3, coff = d0 & 7;
    float a0 = 0.f, a1 = 0.f;
    #pragma unroll 8
    for (int s = sg * 32; s < sg * 32 + 32; ++s) {
        const unsigned u = *(const unsigned*)(As + s * 512 + ((cb ^ (s & 7)) * 8) + coff);
        const float w = pbuf[s];
        a0 += w * bits2f(u << 16);
        a1 += w * bits2f(u & 0xffff0000u);
    }
    if (sg) { cbuf[d0] = a0; cbuf[d0 + 1] = a1; }
    __syncthreads();
    if (!sg) {
        a0 += cbuf[d0];
        a1 += cbuf[d0 + 1];
        ctxp[(long)mt * 512 + d0]     = a0;
        ctxp[(long)mt * 512 + d0 + 1] = a1;
    }
}

// ---- finalize: merge 64 tiles per batch; att + hidden_output ----
__global__ void final2_kernel(const float* __restrict__ e_ws,
                              const float* __restrict__ mstats,
                              const float* __restrict__ ctxp,
                              const float* __restrict__ mask,
                              const float* __restrict__ targ,
                              float* __restrict__ att,
                              float* __restrict__ outh) {
    const int b = blockIdx.x, tid = threadIdx.x;
    __shared__ float wL[64];
    __shared__ float bc[2];
    if (tid < 64) {
        const float mv = mstats[(b * 64 + tid) * 2];
        const float sv = mstats[(b * 64 + tid) * 2 + 1];
        float M = mv;
        #pragma unroll
        for (int m = 1; m <= 32; m <<= 1) M = fmaxf(M, __shfl_xor(M, m));
        float sc = sv * exp2f((mv - M) * L2E);
        #pragma unroll
        for (int m = 1; m <= 32; m <<= 1) sc += __shfl_xor(sc, m);
        wL[tid] = exp2f((mv - M) * L2E) / sc;
        if (tid == 0) { bc[0] = M; bc[1] = sc; }
    }
    __syncthreads();
    const float M = bc[0], invS = 1.0f / bc[1];
    #pragma unroll
    for (int i = 0; i < 16; i++) {
        const int s = i * 256 + tid;
        const long idx = (long)b * 4096 + s;
        att[idx] = exp2f((e_ws[idx] - M) * L2E) * invS * mask[idx];
    }
    #pragma unroll
    for (int dd = 0; dd < 2; dd++) {
        const int d = dd * 256 + tid;
        float a = targ[b * 512 + d];
        #pragma unroll 4
        for (int L = 0; L < 64; L++)
            a += wL[L] * ctxp[((long)(b * 64 + L)) * 512 + d];
        outh[b * 512 + d] = a;
    }
}

extern "C" void kernel_launch(void* const* d_in, const int* in_sizes, int n_in,
                              void* d_out, int out_size, void* d_ws, size_t ws_size,
                              hipStream_t stream) {
    const float* targ = (const float*)d_in[0];
    const float* src  = (const float*)d_in[1];
    const float* mask = (const float*)d_in[2];
    const float* W    = (const float*)d_in[3];
    const float* V    = (const float*)d_in[4];

    float* att  = (float*)d_out;
    float* outh = (float*)d_out + 131072;

    char* ws = (char*)d_ws;
    short* wbf   = (short*)(ws + WS_WBF);
    float* t     = (float*)(ws + WS_T);
    float* e     = (float*)(ws + WS_E);
    float* mst   = (float*)(ws + WS_MST);
    float* ctxp  = (float*)(ws + WS_CTXP);

    prep_kernel<<<256, 256, 0, stream>>>(W, targ, wbf, t);
    fused_kernel<<<2048, 512, 0, stream>>>(src, wbf, t, V, mask, e, mst, ctxp);
    final2_kernel<<<32, 256, 0, stream>>>(e, mst, ctxp, mask, targ, att, outh);
}